// Round 7
// baseline (943.540 us; speedup 1.0000x reference)
//
#include <hip/hip_runtime.h>
#include <cstddef>

// SkipGRU on MI355X (gfx950) — round 12.
// = round 11 (persistent all-16-steps gru_all, per-nb atomic sync, counted
//   vmcnt pipeline, spin placed at kt=13 so it hides under x@W chunks) with
//   ONE change: PLAIN launch instead of hipLaunchCooperativeKernel. Round 11
//   failed with absmax == plausible max|ref| and dur=NaN -> the cooperative
//   launch inside graph capture never ran; output stayed zero. Residency for
//   the spin-sync comes from arithmetic instead: 256-thread blocks, 64KB LDS,
//   ~160 VGPR -> exactly 2 blocks/CU x 256 CU = 512-block grid co-resident;
//   each sync group (8 blocks of one nb) lives in a contiguous 64-block idx
//   window, so even partial in-order dispatch cannot deadlock.
//
// Layouts (round 7):
//  xb[t][nb(64)][kt(16)][g(4)][row(64)][8] bf16 granules (16B).
//  Bt[cc(24)][kt(32)][g(4)][col(64)][8]    (cc = 64 gemm-cols).
//  h ping-pong: same granule layout as xb per nb.

typedef unsigned short u16;
typedef __attribute__((ext_vector_type(8))) short short8;
typedef __attribute__((ext_vector_type(8))) u16 u16x8;
typedef __attribute__((ext_vector_type(4))) float floatx4;

#define MFMA16(a, b, c) __builtin_amdgcn_mfma_f32_16x16x32_bf16((a), (b), (c), 0, 0, 0)

__device__ __forceinline__ u16 f32_to_bf16(float f) {
  union { float f; unsigned int u; } c; c.f = f;
  unsigned int u = c.u + 0x7FFFu + ((c.u >> 16) & 1u);  // RNE
  return (u16)(u >> 16);
}
__device__ __forceinline__ float bf16_to_f32(u16 v) {
  union { unsigned int u; float f; } c; c.u = ((unsigned int)v) << 16;
  return c.f;
}
__device__ __forceinline__ float sigmoidf_(float x) {
  return 1.0f / (1.0f + __expf(-x));
}
__device__ __forceinline__ void gload_lds16(const void* g, void* l) {
  __builtin_amdgcn_global_load_lds(
      (const __attribute__((address_space(1))) unsigned int*)g,
      (__attribute__((address_space(3))) unsigned int*)l, 16, 0, 0);
}

// ---------------------------------------------------------------------------
// pack_x: coalesced. Block = one (t, nb): 64 rows x 512 c. (unchanged)
// ---------------------------------------------------------------------------
__global__ __launch_bounds__(256)
void pack_x(const float* __restrict__ x, u16* __restrict__ xb) {
  __shared__ u16 sm[64 * 512];              // 64KB
  const int t = blockIdx.x >> 6;
  const int nb = blockIdx.x & 63;
  const int tid = threadIdx.x;
#pragma unroll
  for (int it = 0; it < 16; ++it) {
    int idx = it * 256 + tid;
    int row = idx >> 6, ch = idx & 63;      // row 0..63, ch = 8-float chunk
    int xrow = (nb * 2 + (row >> 5)) * 512 + t * 32 + (row & 31);
    const float* src = x + (size_t)xrow * 512 + ch * 8;
    floatx4 va = *(const floatx4*)src;
    floatx4 vb = *(const floatx4*)(src + 4);
    u16x8 pk;
    pk[0] = f32_to_bf16(va[0]); pk[1] = f32_to_bf16(va[1]);
    pk[2] = f32_to_bf16(va[2]); pk[3] = f32_to_bf16(va[3]);
    pk[4] = f32_to_bf16(vb[0]); pk[5] = f32_to_bf16(vb[1]);
    pk[6] = f32_to_bf16(vb[2]); pk[7] = f32_to_bf16(vb[3]);
    *(u16x8*)&sm[row * 512 + (ch ^ (row & 7)) * 8] = pk;
  }
  __syncthreads();
  u16* dst = xb + (size_t)blockIdx.x * 32768;   // blockIdx = t*64+nb = layout order
#pragma unroll
  for (int it = 0; it < 16; ++it) {
    int idx = it * 256 + tid;
    int row = idx & 63, g = (idx >> 6) & 3, kt = idx >> 8;
    int ch = kt * 4 + g;
    u16x8 vv = *(const u16x8*)&sm[row * 512 + (ch ^ (row & 7)) * 8];
    *(u16x8*)(dst + (size_t)idx * 8) = vv;
  }
}

// ---------------------------------------------------------------------------
// pack_Bt: [W;U] -> Bt bf16 [cc(24)][kt(32)][g(4)][col(64)][8] (unchanged)
// ---------------------------------------------------------------------------
__global__ void pack_Bt(const float* __restrict__ W, const float* __restrict__ U,
                        u16* __restrict__ Bt) {
  size_t gid = (size_t)blockIdx.x * 256 + threadIdx.x;   // < 196608
  int col = (int)(gid & 63);
  int g   = (int)((gid >> 6) & 3);
  int kt  = (int)((gid >> 8) & 31);
  int cc  = (int)(gid >> 13);
  int c = cc * 64 + col;
  int k0 = kt * 32 + g * 8;
  u16x8 pk;
#pragma unroll
  for (int j = 0; j < 8; ++j) {
    int k = k0 + j;
    float v = (k < 512) ? W[(size_t)k * 1536 + c] : U[(size_t)(k - 512) * 1536 + c];
    pk[j] = f32_to_bf16(v);
  }
  *(u16x8*)(Bt + gid * 8) = pk;
}

// ---------------------------------------------------------------------------
// gru_all: persistent kernel — ALL 16 timesteps. PLAIN launch, grid 512 x 256
// (2 blocks/CU -> whole grid co-resident). XCD-swizzle: nb=(idx>>6)*8+(idx&7),
// hb=(idx>>3)&7 (8 blocks sharing an nb have the same idx&7 -> one XCD).
// Per-nb sync: cnt[nb] monotone; arrive(release) after h-write; spin(acquire)
// at kt=13 so the wait overlaps 13 chunks of h-independent x@W compute.
// ---------------------------------------------------------------------------
__global__ __launch_bounds__(256)
void gru_all(const u16* __restrict__ xb, const u16* __restrict__ Bt,
             const float* __restrict__ bias,
             u16* __restrict__ h0, u16* __restrict__ h1,
             float* __restrict__ out, unsigned int* __restrict__ cnt) {
  __shared__ alignas(16) char sm[65536];    // 4 x 16KB ring -> 2 blocks/CU
  const int tid = threadIdx.x;
  const int idx = blockIdx.x;
  const int nb = ((idx >> 6) << 3) | (idx & 7);   // 0..63
  const int hb = (idx >> 3) & 7;                  // 0..7
  const int w = __builtin_amdgcn_readfirstlane(tid >> 6);  // SGPR wave id
  const int lane = tid & 63;
  const int wy = w >> 1, wx = w & 1;
  const int q = lane >> 4, lc = lane & 15;
  const int cs0 = hb, cs1 = 8 + hb, cs2 = 16 + hb;
  const int wo = w * 1024;
  const float* b0 = bias;
  const float* b1 = bias + 1536;
  unsigned int* myc = cnt + nb;

  for (int t = 0; t < 16; ++t) {
    const int first = (t == 0) ? 1 : 0;
    const int last  = (t == 15) ? 1 : 0;
    const u16* hinF = (t & 1) ? h1 : h0;    // t=0 never reads h
    u16* houtF      = (t & 1) ? h0 : h1;
    const u16* xbB = xb + (size_t)(t * 64 + nb) * 32768;
    const u16* htB = hinF + (size_t)nb * 32768;

    floatx4 acZ[2][2] = {{{0.f,0.f,0.f,0.f},{0.f,0.f,0.f,0.f}},{{0.f,0.f,0.f,0.f},{0.f,0.f,0.f,0.f}}};
    floatx4 acR[2][2] = {{{0.f,0.f,0.f,0.f},{0.f,0.f,0.f,0.f}},{{0.f,0.f,0.f,0.f},{0.f,0.f,0.f,0.f}}};
    floatx4 acX[2][2] = {{{0.f,0.f,0.f,0.f},{0.f,0.f,0.f,0.f}},{{0.f,0.f,0.f,0.f},{0.f,0.f,0.f,0.f}}};
    floatx4 acH[2][2] = {{{0.f,0.f,0.f,0.f},{0.f,0.f,0.f,0.f}},{{0.f,0.f,0.f,0.f},{0.f,0.f,0.f,0.f}}};

    // Stage K-chunk kt (A 4KB + 3 gate-B 4KB) into ring slot kt&3.
    auto stage = [&](int kt) {
      char* lds = sm + (kt & 3) * 16384;
      const char* aS = (const char*)((kt < 16) ? (xbB + (size_t)kt * 2048)
                                               : (htB + (size_t)(kt - 16) * 2048));
      gload_lds16(aS + wo + lane * 16, lds + wo);
      gload_lds16((const char*)(Bt + (size_t)(cs0 * 32 + kt) * 2048) + wo + lane * 16,
                  lds + 4096 + wo);
      gload_lds16((const char*)(Bt + (size_t)(cs1 * 32 + kt) * 2048) + wo + lane * 16,
                  lds + 8192 + wo);
      gload_lds16((const char*)(Bt + (size_t)(cs2 * 32 + kt) * 2048) + wo + lane * 16,
                  lds + 12288 + wo);
    };
    auto compute = [&](int slot, floatx4 (&acT)[2][2]) {
      const char* lds = sm + slot * 16384;
      short8 a0 = *(const short8*)(lds + (q * 64 + wy * 32 + lc) * 16);
      short8 a1 = *(const short8*)(lds + (q * 64 + wy * 32 + 16 + lc) * 16);
#pragma unroll
      for (int ci = 0; ci < 2; ++ci) {
        int co = (q * 64 + wx * 32 + ci * 16 + lc) * 16;
        short8 bz = *(const short8*)(lds + 4096 + co);
        short8 br = *(const short8*)(lds + 8192 + co);
        short8 bh = *(const short8*)(lds + 12288 + co);
        acZ[0][ci] = MFMA16(a0, bz, acZ[0][ci]);
        acZ[1][ci] = MFMA16(a1, bz, acZ[1][ci]);
        acR[0][ci] = MFMA16(a0, br, acR[0][ci]);
        acR[1][ci] = MFMA16(a1, br, acR[1][ci]);
        acT[0][ci] = MFMA16(a0, bh, acT[0][ci]);
        acT[1][ci] = MFMA16(a1, bh, acT[1][ci]);
      }
    };

    stage(0); stage(1); stage(2);
    if (first) {
      for (int kt = 0; kt < 14; ++kt) {
        asm volatile("s_waitcnt vmcnt(8)" ::: "memory");
        __builtin_amdgcn_s_barrier();
        if (kt < 13) stage(kt + 3);
        __builtin_amdgcn_s_setprio(1);
        compute(kt & 3, acX);
        __builtin_amdgcn_s_setprio(0);
      }
      asm volatile("s_waitcnt vmcnt(4)" ::: "memory");
      __builtin_amdgcn_s_barrier();
      __builtin_amdgcn_s_setprio(1);
      compute(2, acX);                       // kt=14
      __builtin_amdgcn_s_setprio(0);
      asm volatile("s_waitcnt vmcnt(0)" ::: "memory");
      __builtin_amdgcn_s_barrier();
      __builtin_amdgcn_s_setprio(1);
      compute(3, acX);                       // kt=15
      __builtin_amdgcn_s_setprio(0);
    } else {
      for (int kt = 0; kt < 13; ++kt) {      // chunks 0..12 (x@W, no h dep)
        asm volatile("s_waitcnt vmcnt(8)" ::: "memory");
        __builtin_amdgcn_s_barrier();
        stage(kt + 3);                       // 3..15
        __builtin_amdgcn_s_setprio(1);
        compute(kt & 3, acX);
        __builtin_amdgcn_s_setprio(0);
      }
      // kt=13: wait for same-nb h writes of step t-1, then first h stage.
      asm volatile("s_waitcnt vmcnt(8)" ::: "memory");
      __builtin_amdgcn_s_barrier();
      {
        const unsigned int tgt = 8u * (unsigned int)t;
        while (__hip_atomic_load(myc, __ATOMIC_ACQUIRE,
                                 __HIP_MEMORY_SCOPE_AGENT) < tgt)
          __builtin_amdgcn_s_sleep(2);
      }
      stage(16);
      __builtin_amdgcn_s_setprio(1);
      compute(1, acX);                       // kt=13
      __builtin_amdgcn_s_setprio(0);
      asm volatile("s_waitcnt vmcnt(8)" ::: "memory");
      __builtin_amdgcn_s_barrier();
      stage(17);
      __builtin_amdgcn_s_setprio(1);
      compute(2, acX);                       // kt=14
      __builtin_amdgcn_s_setprio(0);
      asm volatile("s_waitcnt vmcnt(8)" ::: "memory");
      __builtin_amdgcn_s_barrier();
      stage(18);
      __builtin_amdgcn_s_setprio(1);
      compute(3, acX);                       // kt=15
      __builtin_amdgcn_s_setprio(0);
      for (int kt = 16; kt < 29; ++kt) {     // chunks 16..28 (h@U)
        asm volatile("s_waitcnt vmcnt(8)" ::: "memory");
        __builtin_amdgcn_s_barrier();
        stage(kt + 3);                       // 19..31
        __builtin_amdgcn_s_setprio(1);
        compute(kt & 3, acH);
        __builtin_amdgcn_s_setprio(0);
      }
      asm volatile("s_waitcnt vmcnt(8)" ::: "memory");
      __builtin_amdgcn_s_barrier();
      __builtin_amdgcn_s_setprio(1);
      compute(1, acH);                       // kt=29
      __builtin_amdgcn_s_setprio(0);
      asm volatile("s_waitcnt vmcnt(4)" ::: "memory");
      __builtin_amdgcn_s_barrier();
      __builtin_amdgcn_s_setprio(1);
      compute(2, acH);                       // kt=30
      __builtin_amdgcn_s_setprio(0);
      asm volatile("s_waitcnt vmcnt(0)" ::: "memory");
      __builtin_amdgcn_s_barrier();
      __builtin_amdgcn_s_setprio(1);
      compute(3, acH);                       // kt=31
      __builtin_amdgcn_s_setprio(0);
    }

    // ---- Epilogue. C/D layout: col = lane&15, row = q*4 + reg.
    __syncthreads();                         // all compute done
    u16* Ct = (u16*)(sm + 49152);            // slot-3 area: 64 x 72 u16 (9KB)
#pragma unroll
    for (int ci = 0; ci < 2; ++ci) {
      const int hcl = wx * 32 + ci * 16 + lc;    // 0..63
      const int hg = hb * 64 + hcl;              // 0..511
      const float bz = b0[hg] + b1[hg];
      const float br = b0[512 + hg] + b1[512 + hg];
      const float b0h = b0[1024 + hg];
      const float b1h = b1[1024 + hg];
      const int ktg = hg >> 5;
      const int gg = (hg >> 3) & 3;
      const size_t hbase = (((size_t)nb * 16 + ktg) * 4 + gg) * 64;
#pragma unroll
      for (int mi = 0; mi < 2; ++mi) {
#pragma unroll
        for (int reg = 0; reg < 4; ++reg) {
          const int nl = wy * 32 + mi * 16 + q * 4 + reg;   // 0..63
          const int n = nb * 64 + nl;
          float z = sigmoidf_(acZ[mi][ci][reg] + bz);
          float r = sigmoidf_(acR[mi][ci][reg] + br);
          float hh = acX[mi][ci][reg] + b0h + r * (acH[mi][ci][reg] + b1h);
          hh = fmaxf(hh, 0.0f);
          float hp = 0.0f;
          if (!first) hp = bf16_to_f32(hinF[(hbase + nl) * 8 + (hg & 7)]);
          float v = z * hp + (1.0f - z) * hh;
          if (last) out[(size_t)n * 512 + hg] = v;
          else      Ct[nl * 72 + hcl] = f32_to_bf16(v);
        }
      }
    }
    if (!last) {
      __syncthreads();
      // Re-emit h in granule layout: 512 granules (row64 x g4 x ktl2), 2/thr.
#pragma unroll
      for (int i = 0; i < 2; ++i) {
        int e = i * 256 + tid;
        int row = e & 63;
        int g = (e >> 6) & 3;
        int ktl = e >> 8;                       // 0..1
        u16x8 vv = *(const u16x8*)(Ct + row * 72 + ktl * 32 + g * 8);
        *(u16x8*)(houtF + ((((size_t)nb * 16 + (hb * 2 + ktl)) * 4 + g) * 64 + row) * 8) = vv;
      }
      __syncthreads();                       // all waves' h stores drained
      if (tid == 0)
        __hip_atomic_fetch_add(myc, 1u, __ATOMIC_RELEASE,
                               __HIP_MEMORY_SCOPE_AGENT);
    }
  }
}

// ---------------------------------------------------------------------------
extern "C" void kernel_launch(void* const* d_in, const int* in_sizes, int n_in,
                              void* d_out, int out_size, void* d_ws, size_t ws_size,
                              hipStream_t stream) {
  const float* x = (const float*)d_in[0];    // (128,512,512)
  const float* W = (const float*)d_in[1];    // (512,1536)
  const float* U = (const float*)d_in[2];    // (512,1536)
  const float* bias = (const float*)d_in[3]; // (2,1536)
  float* out = (float*)d_out;                // (128,16384)

  u16* xb = (u16*)d_ws;                      // 64 MiB
  u16* Bt = xb + (size_t)16 * 64 * 32768;    // 3 MiB
  u16* h0 = Bt + (size_t)1536 * 1024;        // 4 MiB
  u16* h1 = h0 + (size_t)4096 * 512;         // 4 MiB
  unsigned int* cnt = (unsigned int*)(h1 + (size_t)4096 * 512);  // 64 u32

  hipMemsetAsync(cnt, 0, 64 * sizeof(unsigned int), stream);
  pack_x<<<1024, 256, 0, stream>>>(x, xb);
  pack_Bt<<<768, 256, 0, stream>>>(W, U, Bt);
  gru_all<<<512, 256, 0, stream>>>(xb, Bt, bias, h0, h1, out, cnt);
}

// Round 8
// 602.303 us; speedup vs baseline: 1.5666x; 1.5666x over previous
//
#include <hip/hip_runtime.h>
#include <cstddef>

// SkipGRU on MI355X (gfx950) — round 13.
// Persistent kernels abandoned (round 12: 48us/step, spin/acquire overhead >
// launch overhead). Back to the 16-launch round-7 champion (503.6us) with ONE
// change: r=4 register blocking done CLEANLY (round 8's r=4 attempt was
// confounded by K-split reduction + 8-wave sync).
//   gru_step: block tile 128n x 192c, STILL 4 waves (wave = 64x96:
//   4 A-frags x 6 B-frags = 24 MFMA / 10 ds_read_b128, ratio 2.4 vs 1.5),
//   grid 256 (1 block/CU), LDS 3 x 20KB ring, counted vmcnt(5), uniform
//   5 gload_lds/wave/stage. Per-CU LDS traffic per chunk: 96KB -> 60KB —
//   the measured binding resource (per-CU: LDS ~1150cyc vs MFMA 466cyc).
//
// Layouts (unchanged):
//  xb[t][nb(64)][kt(16)][g(4)][row(64)][8] bf16 granules (16B).
//  Bt[cc(24)][kt(32)][g(4)][col(64)][8]    (cc = 64 gemm-cols).
//  h ping-pong: same granule layout as xb per nb.
// LDS slot (20KB): A 8KB [ah(2)][g(4)][row64][16B] + B 12KB
//  [gate(3)][g(4)][col64][16B]; part p (0..19) at byte p*1024.

typedef unsigned short u16;
typedef __attribute__((ext_vector_type(8))) short short8;
typedef __attribute__((ext_vector_type(8))) u16 u16x8;
typedef __attribute__((ext_vector_type(4))) float floatx4;

#define MFMA16(a, b, c) __builtin_amdgcn_mfma_f32_16x16x32_bf16((a), (b), (c), 0, 0, 0)

__device__ __forceinline__ u16 f32_to_bf16(float f) {
  union { float f; unsigned int u; } c; c.f = f;
  unsigned int u = c.u + 0x7FFFu + ((c.u >> 16) & 1u);  // RNE
  return (u16)(u >> 16);
}
__device__ __forceinline__ float bf16_to_f32(u16 v) {
  union { unsigned int u; float f; } c; c.u = ((unsigned int)v) << 16;
  return c.f;
}
__device__ __forceinline__ float sigmoidf_(float x) {
  return 1.0f / (1.0f + __expf(-x));
}
__device__ __forceinline__ void gload_lds16(const void* g, void* l) {
  __builtin_amdgcn_global_load_lds(
      (const __attribute__((address_space(1))) unsigned int*)g,
      (__attribute__((address_space(3))) unsigned int*)l, 16, 0, 0);
}

// ---------------------------------------------------------------------------
// pack_x: coalesced. Block = one (t, nb): 64 rows x 512 c. (unchanged)
// ---------------------------------------------------------------------------
__global__ __launch_bounds__(256)
void pack_x(const float* __restrict__ x, u16* __restrict__ xb) {
  __shared__ u16 sm[64 * 512];              // 64KB
  const int t = blockIdx.x >> 6;
  const int nb = blockIdx.x & 63;
  const int tid = threadIdx.x;
#pragma unroll
  for (int it = 0; it < 16; ++it) {
    int idx = it * 256 + tid;
    int row = idx >> 6, ch = idx & 63;      // row 0..63, ch = 8-float chunk
    int xrow = (nb * 2 + (row >> 5)) * 512 + t * 32 + (row & 31);
    const float* src = x + (size_t)xrow * 512 + ch * 8;
    floatx4 va = *(const floatx4*)src;
    floatx4 vb = *(const floatx4*)(src + 4);
    u16x8 pk;
    pk[0] = f32_to_bf16(va[0]); pk[1] = f32_to_bf16(va[1]);
    pk[2] = f32_to_bf16(va[2]); pk[3] = f32_to_bf16(va[3]);
    pk[4] = f32_to_bf16(vb[0]); pk[5] = f32_to_bf16(vb[1]);
    pk[6] = f32_to_bf16(vb[2]); pk[7] = f32_to_bf16(vb[3]);
    *(u16x8*)&sm[row * 512 + (ch ^ (row & 7)) * 8] = pk;
  }
  __syncthreads();
  u16* dst = xb + (size_t)blockIdx.x * 32768;   // blockIdx = t*64+nb = layout order
#pragma unroll
  for (int it = 0; it < 16; ++it) {
    int idx = it * 256 + tid;
    int row = idx & 63, g = (idx >> 6) & 3, kt = idx >> 8;
    int ch = kt * 4 + g;
    u16x8 vv = *(const u16x8*)&sm[row * 512 + (ch ^ (row & 7)) * 8];
    *(u16x8*)(dst + (size_t)idx * 8) = vv;
  }
}

// ---------------------------------------------------------------------------
// pack_Bt: [W;U] -> Bt bf16 [cc(24)][kt(32)][g(4)][col(64)][8] (unchanged)
// ---------------------------------------------------------------------------
__global__ void pack_Bt(const float* __restrict__ W, const float* __restrict__ U,
                        u16* __restrict__ Bt) {
  size_t gid = (size_t)blockIdx.x * 256 + threadIdx.x;   // < 196608
  int col = (int)(gid & 63);
  int g   = (int)((gid >> 6) & 3);
  int kt  = (int)((gid >> 8) & 31);
  int cc  = (int)(gid >> 13);
  int c = cc * 64 + col;
  int k0 = kt * 32 + g * 8;
  u16x8 pk;
#pragma unroll
  for (int j = 0; j < 8; ++j) {
    int k = k0 + j;
    float v = (k < 512) ? W[(size_t)k * 1536 + c] : U[(size_t)(k - 512) * 1536 + c];
    pk[j] = f32_to_bf16(v);
  }
  *(u16x8*)(Bt + gid * 8) = pk;
}

// ---------------------------------------------------------------------------
// gru_step: one GRU timestep. Grid 256 (1 block/CU), 256 thr = 4 waves.
// Block tile 128n x 192c; wave (wy,wx) = 64 rows x 96 cols (4 A-frags x
// 3 gates x 2 col-frags = 24 MFMA, 10 ds_read_b128 per chunk).
// XCD swizzle: nbb=(idx>>6)*8+(idx&7) (0..31), hb=(idx>>3)&7.
// LDS: 3 x 20KB ring; counted vmcnt(5), stage 2 ahead, 1 barrier/chunk.
// ---------------------------------------------------------------------------
__global__ __launch_bounds__(256)
void gru_step(const u16* __restrict__ xb, const u16* __restrict__ Bt,
              const float* __restrict__ bias,
              const u16* __restrict__ h_in, u16* __restrict__ h_out,
              float* __restrict__ out, int t, int first, int last) {
  __shared__ alignas(16) char sm[61440];    // 3 x 20KB ring
  const int tid = threadIdx.x;
  const int idx = blockIdx.x;               // 0..255
  const int nbb = ((idx >> 6) << 3) | (idx & 7);   // 0..31 (128-row block)
  const int hb  = (idx >> 3) & 7;                  // 0..7
  const int w = __builtin_amdgcn_readfirstlane(tid >> 6);  // SGPR wave id
  const int lane = tid & 63;
  const int wy = w >> 1, wx = w & 1;
  const int q = lane >> 4, lc = lane & 15;

  const u16* xbB = xb + (size_t)(t * 64 + nbb * 2) * 32768;
  const u16* htB = h_in + (size_t)(nbb * 2) * 32768;

  floatx4 acZ[4][2], acR[4][2], acX[4][2], acH[4][2];
#pragma unroll
  for (int f = 0; f < 4; ++f)
#pragma unroll
    for (int ci = 0; ci < 2; ++ci) {
      acZ[f][ci] = (floatx4){0.f, 0.f, 0.f, 0.f};
      acR[f][ci] = (floatx4){0.f, 0.f, 0.f, 0.f};
      acX[f][ci] = (floatx4){0.f, 0.f, 0.f, 0.f};
      acH[f][ci] = (floatx4){0.f, 0.f, 0.f, 0.f};
    }

  // Stage chunk kt into ring slot: 20 x 1KB parts, 5 per wave (p = i*4+w,
  // scalar). p<8 -> A [ah=p>>2][g=p&3]; p>=8 -> B [gate=(p-8)>>2][g=(p-8)&3].
  // LDS dst = slot*20480 + p*1024 (wave-uniform).
  auto stage = [&](int kt, int slot) {
    char* L = sm + slot * 20480;
#pragma unroll
    for (int i = 0; i < 5; ++i) {
      int p = i * 4 + w;
      const u16* src;
      if (p < 8) {
        int ah = p >> 2, g = p & 3;
        src = (kt < 16)
                ? xbB + (size_t)ah * 32768 + (size_t)kt * 2048 + (size_t)g * 512
                : htB + (size_t)ah * 32768 + (size_t)(kt - 16) * 2048 + (size_t)g * 512;
      } else {
        int gate = (p - 8) >> 2, g = (p - 8) & 3;
        int cs = gate * 8 + hb;
        src = Bt + (size_t)(cs * 32 + kt) * 2048 + (size_t)g * 512;
      }
      gload_lds16((const char*)src + lane * 16, L + p * 1024);
    }
  };

  // Compute one chunk: 4 A-frags x (3 gates x 2 col-frags) = 24 MFMA,
  // 10 ds_read_b128. acT compile-time bound per call site.
  auto compute = [&](int slot, floatx4 (&acT)[4][2]) {
    const char* L = sm + slot * 20480;
    const char* Ab = L + wy * 4096 + (q * 64 + lc) * 16;
    short8 a0 = *(const short8*)(Ab);
    short8 a1 = *(const short8*)(Ab + 256);
    short8 a2 = *(const short8*)(Ab + 512);
    short8 a3 = *(const short8*)(Ab + 768);
#pragma unroll
    for (int ci = 0; ci < 2; ++ci) {
      const char* Bb = L + 8192 + (q * 64 + wx * 32 + ci * 16 + lc) * 16;
      short8 bz = *(const short8*)(Bb);
      short8 br = *(const short8*)(Bb + 4096);
      short8 bh = *(const short8*)(Bb + 8192);
      acZ[0][ci] = MFMA16(a0, bz, acZ[0][ci]);
      acZ[1][ci] = MFMA16(a1, bz, acZ[1][ci]);
      acZ[2][ci] = MFMA16(a2, bz, acZ[2][ci]);
      acZ[3][ci] = MFMA16(a3, bz, acZ[3][ci]);
      acR[0][ci] = MFMA16(a0, br, acR[0][ci]);
      acR[1][ci] = MFMA16(a1, br, acR[1][ci]);
      acR[2][ci] = MFMA16(a2, br, acR[2][ci]);
      acR[3][ci] = MFMA16(a3, br, acR[3][ci]);
      acT[0][ci] = MFMA16(a0, bh, acT[0][ci]);
      acT[1][ci] = MFMA16(a1, bh, acT[1][ci]);
      acT[2][ci] = MFMA16(a2, bh, acT[2][ci]);
      acT[3][ci] = MFMA16(a3, bh, acT[3][ci]);
    }
  };

  // ---- K-loop: 3-slot ring (slot = kt%3), stage 2 ahead, counted vmcnt.
  // At iter kt: outstanding = stage(kt+1) [5] (+ stage(kt) if not landed);
  // vmcnt(5) -> stage(kt) landed; barrier publishes; stage(kt+2) overwrites
  // slot (kt-1)%3, whose reads all completed inside compute(kt-1) pre-barrier.
  stage(0, 0); stage(1, 1);
  if (first) {
    for (int kt = 0; kt < 14; ++kt) {       // chunks 0..13, acc acX
      asm volatile("s_waitcnt vmcnt(5)" ::: "memory");
      __builtin_amdgcn_s_barrier();
      if (kt < 14) stage(kt + 2, (kt + 2) % 3);
      __builtin_amdgcn_s_setprio(1);
      compute(kt % 3, acX);
      __builtin_amdgcn_s_setprio(0);
    }
    asm volatile("s_waitcnt vmcnt(5)" ::: "memory");
    __builtin_amdgcn_s_barrier();
    __builtin_amdgcn_s_setprio(1);
    compute(14 % 3, acX);                   // kt=14
    __builtin_amdgcn_s_setprio(0);
    asm volatile("s_waitcnt vmcnt(0)" ::: "memory");
    __builtin_amdgcn_s_barrier();
    __builtin_amdgcn_s_setprio(1);
    compute(15 % 3, acX);                   // kt=15
    __builtin_amdgcn_s_setprio(0);
  } else {
    for (int kt = 0; kt < 16; ++kt) {       // chunks 0..15 (x@W), acc acX
      asm volatile("s_waitcnt vmcnt(5)" ::: "memory");
      __builtin_amdgcn_s_barrier();
      stage(kt + 2, (kt + 2) % 3);          // 2..17, always valid
      __builtin_amdgcn_s_setprio(1);
      compute(kt % 3, acX);
      __builtin_amdgcn_s_setprio(0);
    }
    for (int kt = 16; kt < 30; ++kt) {      // chunks 16..29 (h@U), acc acH
      asm volatile("s_waitcnt vmcnt(5)" ::: "memory");
      __builtin_amdgcn_s_barrier();
      stage(kt + 2, (kt + 2) % 3);          // 18..31
      __builtin_amdgcn_s_setprio(1);
      compute(kt % 3, acH);
      __builtin_amdgcn_s_setprio(0);
    }
    asm volatile("s_waitcnt vmcnt(5)" ::: "memory");
    __builtin_amdgcn_s_barrier();
    __builtin_amdgcn_s_setprio(1);
    compute(30 % 3, acH);                   // kt=30
    __builtin_amdgcn_s_setprio(0);
    asm volatile("s_waitcnt vmcnt(0)" ::: "memory");
    __builtin_amdgcn_s_barrier();
    __builtin_amdgcn_s_setprio(1);
    compute(31 % 3, acH);                   // kt=31
    __builtin_amdgcn_s_setprio(0);
  }

  // ---- Epilogue. C/D layout: col = lane&15, row = q*4 + reg.
  __syncthreads();                          // all compute done before Ct reuse
  const float* b0 = bias;
  const float* b1 = bias + 1536;
  u16* Ct = (u16*)sm;                       // 128 rows x 72 u16 (18KB)
#pragma unroll
  for (int ci = 0; ci < 2; ++ci) {
    const int hcl = wx * 32 + ci * 16 + lc;     // 0..63
    const int hg = hb * 64 + hcl;               // 0..511
    const float bz = b0[hg] + b1[hg];
    const float br = b0[512 + hg] + b1[512 + hg];
    const float b0h = b0[1024 + hg];
    const float b1h = b1[1024 + hg];
    const int ktg = hg >> 5;
    const int gg = (hg >> 3) & 3;
    const int nb2 = nbb * 2 + wy;               // this wave's nb half
    const size_t hbase = (((size_t)nb2 * 16 + ktg) * 4 + gg) * 64;
#pragma unroll
    for (int f = 0; f < 4; ++f) {
#pragma unroll
      for (int reg = 0; reg < 4; ++reg) {
        const int rowl = f * 16 + q * 4 + reg;  // 0..63 within wave's half
        const int nl = wy * 64 + rowl;          // 0..127
        const int n = nbb * 128 + nl;
        float z = sigmoidf_(acZ[f][ci][reg] + bz);
        float r = sigmoidf_(acR[f][ci][reg] + br);
        float hh = acX[f][ci][reg] + b0h + r * (acH[f][ci][reg] + b1h);
        hh = fmaxf(hh, 0.0f);
        float hp = 0.0f;
        if (!first) hp = bf16_to_f32(h_in[(hbase + rowl) * 8 + (hg & 7)]);
        float v = z * hp + (1.0f - z) * hh;
        if (last) out[(size_t)n * 512 + hg] = v;
        else      Ct[nl * 72 + hcl] = f32_to_bf16(v);
      }
    }
  }
  if (!last) {
    __syncthreads();
    // Re-emit h in granule layout: 1024 granules (row128 x gc8), 4/thread.
#pragma unroll
    for (int i = 0; i < 4; ++i) {
      int e = i * 256 + tid;                    // 0..1023
      int row = e & 127, gc = e >> 7;           // gc 0..7
      u16x8 vv = *(const u16x8*)(Ct + row * 72 + gc * 8);
      int nb2 = nbb * 2 + (row >> 6);
      int ktg = hb * 2 + (gc >> 2);
      int g = gc & 3;
      *(u16x8*)(h_out + ((((size_t)nb2 * 16 + ktg) * 4 + g) * 64 + (row & 63)) * 8) = vv;
    }
  }
}

// ---------------------------------------------------------------------------
extern "C" void kernel_launch(void* const* d_in, const int* in_sizes, int n_in,
                              void* d_out, int out_size, void* d_ws, size_t ws_size,
                              hipStream_t stream) {
  const float* x = (const float*)d_in[0];    // (128,512,512)
  const float* W = (const float*)d_in[1];    // (512,1536)
  const float* U = (const float*)d_in[2];    // (512,1536)
  const float* bias = (const float*)d_in[3]; // (2,1536)
  float* out = (float*)d_out;                // (128,16384)

  u16* xb = (u16*)d_ws;                      // 64 MiB
  u16* Bt = xb + (size_t)16 * 64 * 32768;    // 3 MiB
  u16* h0 = Bt + (size_t)1536 * 1024;        // 4 MiB
  u16* h1 = h0 + (size_t)4096 * 512;         // 4 MiB

  pack_x<<<1024, 256, 0, stream>>>(x, xb);
  pack_Bt<<<768, 256, 0, stream>>>(W, U, Bt);

  for (int t = 0; t < 16; ++t) {
    const u16* hin = (t & 1) ? h1 : h0;      // t=0 never reads h
    u16* hout = (t & 1) ? h0 : h1;
    gru_step<<<256, 256, 0, stream>>>(
        xb, Bt, bias, hin, hout, out, t, (t == 0) ? 1 : 0, (t == 15) ? 1 : 0);
  }
}